// Round 12
// baseline (260.219 us; speedup 1.0000x reference)
//
#include <hip/hip_runtime.h>

#define N_USERS 100000
#define N_ITEMS 50000
#define N_NODES (N_USERS + N_ITEMS)
#define DIM 64
#define BATCH 16384
#define RPB 256                          // rows per bucket
#define BSHIFT 8                         // log2(RPB)
#define NB ((N_NODES + RPB - 1) / RPB)   // 586 buckets
#define HP 592                           // padded hist stride
#define EPT 4                            // edges per thread in scatter
#define TILE_E (512 * EPT)               // 2048 edges per scatter block
#define STRIDE 7168                      // bcv region stride (48-sigma headroom)
#define XSCALE 64.0f                     // fp8 storage scale
#define INV_XSCALE 0.015625f             // 1/64

struct __align__(8) Pair { int c; float v; };
typedef float floatx2 __attribute__((ext_vector_type(2)));

// ---- fp8 helpers (e4m3, gfx940+ builtins) ---------------------------------
__device__ __forceinline__ unsigned pk8(float a, float b, float c, float d) {
    int w = __builtin_amdgcn_cvt_pk_fp8_f32(a, b, 0, false);
    w = __builtin_amdgcn_cvt_pk_fp8_f32(c, d, w, true);
    return (unsigned)w;
}

// acc(a0..a3) += v * fp8x4(x)   — 2 cvt + 4 fma
#define EDGE_F8D(V, X) { \
    floatx2 lo_ = __builtin_amdgcn_cvt_pk_f32_fp8((X), false); \
    floatx2 hi_ = __builtin_amdgcn_cvt_pk_f32_fp8((X), true); \
    a0 = fmaf((V), lo_.x, a0); a1 = fmaf((V), lo_.y, a1); \
    a2 = fmaf((V), hi_.x, a2); a3 = fmaf((V), hi_.y, a3); }

// non-temporal Pair load (perm stream is read-once per pass)
__device__ __forceinline__ Pair ldnt(const Pair* p) {
    unsigned long long w = __builtin_nontemporal_load((const unsigned long long*)p);
    Pair r;
    r.c = (int)(unsigned)(w & 0xffffffffu);
    r.v = __uint_as_float((unsigned)(w >> 32));
    return r;
}

// ---------------------------------------------------------------------------
__device__ __forceinline__ float block_reduce_sum(float v) {
    for (int s = 32; s > 0; s >>= 1) v += __shfl_xor(v, s, 64);
    __shared__ float sm[8];
    int lane = threadIdx.x & 63;
    int wid  = threadIdx.x >> 6;
    if (lane == 0) sm[wid] = v;
    __syncthreads();
    float t = 0.0f;
    if (threadIdx.x == 0) {
        int nw = (blockDim.x + 63) >> 6;
        for (int w = 0; w < nw; ++w) t += sm[w];
    }
    return t;
}

// ---------------------------------------------------------------------------
// Convert concat [uw;iw] f32 -> fp8 (x64 scale). Also clears flags + bcursor.
// ---------------------------------------------------------------------------
__global__ void convert_kernel(const float* __restrict__ uw, const float* __restrict__ iw,
                               unsigned char* __restrict__ x8,
                               int* __restrict__ flags, int* __restrict__ bcursor) {
    size_t tid = (size_t)blockIdx.x * 256 + threadIdx.x;
    if (tid < N_NODES) flags[tid] = 0;
    else if (tid < N_NODES + NB) bcursor[tid - N_NODES] = 0;
    size_t base = tid * 8;
    if (base >= (size_t)N_NODES * DIM) return;
    const float* src = (base < (size_t)N_USERS * DIM) ? uw + base
                                                      : iw + (base - (size_t)N_USERS * DIM);
    float4 a = ((const float4*)src)[0];
    float4 b = ((const float4*)src)[1];
    uint2 o;
    o.x = pk8(XSCALE * a.x, XSCALE * a.y, XSCALE * a.z, XSCALE * a.w);
    o.y = pk8(XSCALE * b.x, XSCALE * b.y, XSCALE * b.z, XSCALE * b.w);
    *(uint2*)(x8 + base) = o;
}

// ---------------------------------------------------------------------------
// Init: acc_0 = gathered layer-0 embeddings + reg_sum from ORIGINAL weights.
// ---------------------------------------------------------------------------
__global__ void init_kernel(const float* __restrict__ uw, const float* __restrict__ iw,
                            const int* __restrict__ users, const int* __restrict__ pos,
                            const int* __restrict__ neg,
                            float* __restrict__ uacc, float* __restrict__ pacc,
                            float* __restrict__ nacc, float* __restrict__ reg_sum) {
    int tid = blockIdx.x * blockDim.x + threadIdx.x;
    int i = tid >> 4;
    int q = tid & 15;
    if (i >= BATCH) return;
    size_t o = (size_t)i * DIM + q * 4;
    float4 u = *(const float4*)(uw + (size_t)users[i] * DIM + q * 4);
    float4 p = *(const float4*)(iw + (size_t)pos[i]   * DIM + q * 4);
    float4 n = *(const float4*)(iw + (size_t)neg[i]   * DIM + q * 4);
    *(float4*)(uacc + o) = u;
    *(float4*)(pacc + o) = p;
    *(float4*)(nacc + o) = n;
    float ss = u.x*u.x + u.y*u.y + u.z*u.z + u.w*u.w
             + p.x*p.x + p.y*p.y + p.z*p.z + p.w*p.w
             + n.x*n.x + n.y*n.y + n.z*n.z + n.w*n.w;
    float bt = block_reduce_sum(ss);
    if (threadIdx.x == 0) unsafeAtomicAdd(reg_sum, bt);
}

// ---------------------------------------------------------------------------
// Mark rows needed by the final gather; also zero the loss/reg sums.
// ---------------------------------------------------------------------------
__global__ void flag_kernel(const int* __restrict__ users, const int* __restrict__ pos,
                            const int* __restrict__ neg, int* __restrict__ flags,
                            float* __restrict__ sums) {
    int tid = blockIdx.x * blockDim.x + threadIdx.x;
    if (blockIdx.x == 0 && threadIdx.x < 2) sums[threadIdx.x] = 0.0f;
    if (tid < BATCH)               flags[users[tid]] = 1;
    else if (tid < 2 * BATCH)      flags[N_USERS + pos[tid - BATCH]] = 1;
    else if (tid < 3 * BATCH)      flags[N_USERS + neg[tid - 2 * BATCH]] = 1;
}

// ---------------------------------------------------------------------------
// Binned scatter into fixed-stride per-bucket regions. All global loads in
// phase 1; per-wave LDS hist; one packed 8B store per edge.
// packed c-field = col | (row_local << 18)   (col < 2^18, row_local < 256)
// ---------------------------------------------------------------------------
__global__ void binned_scatter_kernel(const int* __restrict__ rows, const int* __restrict__ cols,
                                      const float* __restrict__ vals, int* __restrict__ bcursor,
                                      Pair* __restrict__ bcv, int nnz) {
    __shared__ int h[8][HP];
    int t = threadIdx.x, w = t >> 6;
    for (int i = t; i < 8 * HP; i += 512) ((int*)h)[i] = 0;
    __syncthreads();
    long long tile = (long long)blockIdx.x * TILE_E;
    int er[EPT], cr[EPT];
    float vr[EPT];
    #pragma unroll
    for (int j = 0; j < EPT; ++j) {
        long long e = tile + t + j * 512;
        if (e < nnz) {
            int r = rows[e];
            er[j] = r;
            cr[j] = cols[e];
            vr[j] = vals[e];
            atomicAdd(&h[w][r >> BSHIFT], 1);
        } else er[j] = -1;
    }
    __syncthreads();
    for (int b = t; b < NB; b += 512) {
        int cw[8], tot = 0;
        #pragma unroll
        for (int w2 = 0; w2 < 8; ++w2) { cw[w2] = h[w2][b]; tot += cw[w2]; }
        int base = tot ? (b * STRIDE + atomicAdd(&bcursor[b], tot)) : 0;
        #pragma unroll
        for (int w2 = 0; w2 < 8; ++w2) { h[w2][b] = base; base += cw[w2]; }
    }
    __syncthreads();
    #pragma unroll
    for (int j = 0; j < EPT; ++j) {
        if (er[j] >= 0) {
            int r = er[j];
            int dst = atomicAdd(&h[w][r >> BSHIFT], 1);
            Pair p;
            p.c = cr[j] | ((r & (RPB - 1)) << 18);
            p.v = vr[j];
            bcv[dst] = p;
        }
    }
}

// ---------------------------------------------------------------------------
// Post-scan: bucket counts -> dense CSR bucket bases (NB=586 <= 1024).
// ---------------------------------------------------------------------------
__global__ void post_scan_kernel(const int* __restrict__ counts, int* __restrict__ bbase,
                                 int* __restrict__ rowptr, int nnz) {
    __shared__ int sm[1024];
    int t = threadIdx.x;
    int v = (t < NB) ? counts[t] : 0;
    sm[t] = v;
    __syncthreads();
    for (int off = 1; off < 1024; off <<= 1) {
        int tmp = (t >= off) ? sm[t - off] : 0;
        __syncthreads();
        sm[t] += tmp;
        __syncthreads();
    }
    if (t < NB) bbase[t] = sm[t] - v;
    if (t == 1023) bbase[NB] = sm[1023];
    if (t == 0) rowptr[N_NODES] = nnz;
}

// ---------------------------------------------------------------------------
// Per-bucket counting sort in LDS -> final dense CSR perm + rowptr.
// 256 threads, 586 blocks; 4-way wave-replicated hist.
// ---------------------------------------------------------------------------
__global__ void bucket_sort_kernel(const Pair* __restrict__ bcv,
                                   const int* __restrict__ counts,
                                   const int* __restrict__ bbase,
                                   int* __restrict__ rowptr, Pair* __restrict__ perm) {
    __shared__ int rh8[4][RPB + 8];
    __shared__ int rh[RPB];
    __shared__ int sc[RPB];
    int blk = blockIdx.x;
    int t = threadIdx.x;        // 256 threads
    int w = t >> 6;             // 0..3
    size_t src = (size_t)blk * STRIDE;
    int base = bbase[blk];
    int cnt  = counts[blk];
    for (int i = t; i < 4 * (RPB + 8); i += 256) ((int*)rh8)[i] = 0;
    __syncthreads();
    for (int i = t; i < cnt; i += 256)
        atomicAdd(&rh8[w][(unsigned)bcv[src + i].c >> 18], 1);
    __syncthreads();
    int v = 0;
    #pragma unroll
    for (int w2 = 0; w2 < 4; ++w2) v += rh8[w2][t];
    sc[t] = v;
    __syncthreads();
    for (int off = 1; off < 256; off <<= 1) {
        int tmp = (t >= off) ? sc[t - off] : 0;
        __syncthreads();
        sc[t] += tmp;
        __syncthreads();
    }
    int excl = sc[t] - v;
    int g = blk * RPB + t;
    if (g < N_NODES) rowptr[g] = base + excl;
    rh[t] = excl;
    __syncthreads();
    for (int i = t; i < cnt; i += 256) {
        Pair p = bcv[src + i];
        int r = (unsigned)p.c >> 18;
        int rk = atomicAdd(&rh[r], 1);
        p.c &= 0x3FFFF;
        perm[base + rk] = p;
    }
}

// ---------------------------------------------------------------------------
// CSR SpMM, fp8 in / fp8 out (f32 accumulate). 16 lanes per ROW (one dword
// = 4 dims per lane); 8-deep edge unroll; zero shuffles; nt perm loads.
// ---------------------------------------------------------------------------
template<bool FLAGGED>
__global__ void spmm_csr_f8_kernel(const unsigned char* __restrict__ x8,
                                   const Pair* __restrict__ pe,
                                   const int* __restrict__ rowptr,
                                   const int* __restrict__ flags,
                                   unsigned char* __restrict__ out8) {
    int row = blockIdx.x * 16 + (threadIdx.x >> 4);
    if (row >= N_NODES) return;
    if (FLAGGED && !flags[row]) return;
    int q = threadIdx.x & 15;        // dword slot (4 dims)
    int start = rowptr[row];
    int end   = rowptr[row + 1];
    float a0 = 0.f, a1 = 0.f, a2 = 0.f, a3 = 0.f;
    int e = start;
    for (; e + 7 < end; e += 8) {
        Pair p0 = ldnt(pe + e),     p1 = ldnt(pe + e + 1);
        Pair p2 = ldnt(pe + e + 2), p3 = ldnt(pe + e + 3);
        Pair p4 = ldnt(pe + e + 4), p5 = ldnt(pe + e + 5);
        Pair p6 = ldnt(pe + e + 6), p7 = ldnt(pe + e + 7);
        unsigned x0 = *(const unsigned*)(x8 + ((size_t)p0.c << 6) + q * 4);
        unsigned x1 = *(const unsigned*)(x8 + ((size_t)p1.c << 6) + q * 4);
        unsigned x2 = *(const unsigned*)(x8 + ((size_t)p2.c << 6) + q * 4);
        unsigned x3 = *(const unsigned*)(x8 + ((size_t)p3.c << 6) + q * 4);
        unsigned x4 = *(const unsigned*)(x8 + ((size_t)p4.c << 6) + q * 4);
        unsigned x5 = *(const unsigned*)(x8 + ((size_t)p5.c << 6) + q * 4);
        unsigned x6 = *(const unsigned*)(x8 + ((size_t)p6.c << 6) + q * 4);
        unsigned x7 = *(const unsigned*)(x8 + ((size_t)p7.c << 6) + q * 4);
        EDGE_F8D(p0.v, x0); EDGE_F8D(p1.v, x1);
        EDGE_F8D(p2.v, x2); EDGE_F8D(p3.v, x3);
        EDGE_F8D(p4.v, x4); EDGE_F8D(p5.v, x5);
        EDGE_F8D(p6.v, x6); EDGE_F8D(p7.v, x7);
    }
    for (; e + 1 < end; e += 2) {
        Pair p0 = ldnt(pe + e), p1 = ldnt(pe + e + 1);
        unsigned x0 = *(const unsigned*)(x8 + ((size_t)p0.c << 6) + q * 4);
        unsigned x1 = *(const unsigned*)(x8 + ((size_t)p1.c << 6) + q * 4);
        EDGE_F8D(p0.v, x0); EDGE_F8D(p1.v, x1);
    }
    if (e < end) {
        Pair p = ldnt(pe + e);
        unsigned x = *(const unsigned*)(x8 + ((size_t)p.c << 6) + q * 4);
        EDGE_F8D(p.v, x);
    }
    *(unsigned*)(out8 + ((size_t)row << 6) + q * 4) = pk8(a0, a1, a2, a3);
}

// ---------------------------------------------------------------------------
// Legacy COO atomic SpMM (fallback).
// ---------------------------------------------------------------------------
__global__ void spmm_atomic_kernel(const float* __restrict__ xu, const float* __restrict__ xi,
                                   const float* __restrict__ vals, const int* __restrict__ rows,
                                   const int* __restrict__ cols,
                                   float* __restrict__ out, int nnz) {
    long long tid = (long long)blockIdx.x * blockDim.x + threadIdx.x;
    int e = (int)(tid >> 4);
    if (e >= nnz) return;
    int q = (int)(tid & 15);
    int r = rows[e];
    int c = cols[e];
    float v = vals[e];
    const float* src = (c < N_USERS) ? (xu + (size_t)c * DIM)
                                     : (xi + (size_t)(c - N_USERS) * DIM);
    float4 x = *(const float4*)(src + q * 4);
    float* dst = out + (size_t)r * DIM + q * 4;
    unsafeAtomicAdd(dst + 0, v * x.x);
    unsafeAtomicAdd(dst + 1, v * x.y);
    unsafeAtomicAdd(dst + 2, v * x.z);
    unsafeAtomicAdd(dst + 3, v * x.w);
}

// ---------------------------------------------------------------------------
// Gather-accumulate a layer's fp8 output at the batch rows only (unscale).
// ---------------------------------------------------------------------------
__global__ void gather_add_f8_kernel(const unsigned char* __restrict__ x8,
                                     const int* __restrict__ users, const int* __restrict__ pos,
                                     const int* __restrict__ neg,
                                     float* __restrict__ uacc, float* __restrict__ pacc,
                                     float* __restrict__ nacc) {
    int tid = blockIdx.x * blockDim.x + threadIdx.x;
    int i = tid >> 4;
    int q = tid & 15;
    if (i >= BATCH) return;
    size_t o = (size_t)i * DIM + q * 4;
    float4 a;
    unsigned u;
    floatx2 lo, hi;

    a = *(float4*)(uacc + o);
    u = *(const unsigned*)(x8 + ((size_t)users[i] << 6) + q * 4);
    lo = __builtin_amdgcn_cvt_pk_f32_fp8(u, false);
    hi = __builtin_amdgcn_cvt_pk_f32_fp8(u, true);
    a.x = fmaf(lo.x, INV_XSCALE, a.x); a.y = fmaf(lo.y, INV_XSCALE, a.y);
    a.z = fmaf(hi.x, INV_XSCALE, a.z); a.w = fmaf(hi.y, INV_XSCALE, a.w);
    *(float4*)(uacc + o) = a;

    a = *(float4*)(pacc + o);
    u = *(const unsigned*)(x8 + ((size_t)(N_USERS + pos[i]) << 6) + q * 4);
    lo = __builtin_amdgcn_cvt_pk_f32_fp8(u, false);
    hi = __builtin_amdgcn_cvt_pk_f32_fp8(u, true);
    a.x = fmaf(lo.x, INV_XSCALE, a.x); a.y = fmaf(lo.y, INV_XSCALE, a.y);
    a.z = fmaf(hi.x, INV_XSCALE, a.z); a.w = fmaf(hi.y, INV_XSCALE, a.w);
    *(float4*)(pacc + o) = a;

    a = *(float4*)(nacc + o);
    u = *(const unsigned*)(x8 + ((size_t)(N_USERS + neg[i]) << 6) + q * 4);
    lo = __builtin_amdgcn_cvt_pk_f32_fp8(u, false);
    hi = __builtin_amdgcn_cvt_pk_f32_fp8(u, true);
    a.x = fmaf(lo.x, INV_XSCALE, a.x); a.y = fmaf(lo.y, INV_XSCALE, a.y);
    a.z = fmaf(hi.x, INV_XSCALE, a.z); a.w = fmaf(hi.y, INV_XSCALE, a.w);
    *(float4*)(nacc + o) = a;
}

// ---------------------------------------------------------------------------
// Fused layer-3 gather + BPR score. final = acc/4, so dot scales by 1/16.
// ---------------------------------------------------------------------------
__global__ void gather_score_kernel(const unsigned char* __restrict__ x8,
                                    const int* __restrict__ users, const int* __restrict__ pos,
                                    const int* __restrict__ neg,
                                    const float* __restrict__ uacc, const float* __restrict__ pacc,
                                    const float* __restrict__ nacc, float* __restrict__ loss_sum) {
    int tid = blockIdx.x * blockDim.x + threadIdx.x;
    int i = tid >> 4;
    int q = tid & 15;
    float ps = 0.0f, ns = 0.0f;
    if (i < BATCH) {
        size_t o = (size_t)i * DIM + q * 4;
        float4 u = *(const float4*)(uacc + o);
        float4 p = *(const float4*)(pacc + o);
        float4 n = *(const float4*)(nacc + o);
        unsigned t;
        floatx2 lo, hi;
        t = *(const unsigned*)(x8 + ((size_t)users[i] << 6) + q * 4);
        lo = __builtin_amdgcn_cvt_pk_f32_fp8(t, false);
        hi = __builtin_amdgcn_cvt_pk_f32_fp8(t, true);
        u.x = fmaf(lo.x, INV_XSCALE, u.x); u.y = fmaf(lo.y, INV_XSCALE, u.y);
        u.z = fmaf(hi.x, INV_XSCALE, u.z); u.w = fmaf(hi.y, INV_XSCALE, u.w);
        t = *(const unsigned*)(x8 + ((size_t)(N_USERS + pos[i]) << 6) + q * 4);
        lo = __builtin_amdgcn_cvt_pk_f32_fp8(t, false);
        hi = __builtin_amdgcn_cvt_pk_f32_fp8(t, true);
        p.x = fmaf(lo.x, INV_XSCALE, p.x); p.y = fmaf(lo.y, INV_XSCALE, p.y);
        p.z = fmaf(hi.x, INV_XSCALE, p.z); p.w = fmaf(hi.y, INV_XSCALE, p.w);
        t = *(const unsigned*)(x8 + ((size_t)(N_USERS + neg[i]) << 6) + q * 4);
        lo = __builtin_amdgcn_cvt_pk_f32_fp8(t, false);
        hi = __builtin_amdgcn_cvt_pk_f32_fp8(t, true);
        n.x = fmaf(lo.x, INV_XSCALE, n.x); n.y = fmaf(lo.y, INV_XSCALE, n.y);
        n.z = fmaf(hi.x, INV_XSCALE, n.z); n.w = fmaf(hi.y, INV_XSCALE, n.w);
        ps = u.x*p.x + u.y*p.y + u.z*p.z + u.w*p.w;
        ns = u.x*n.x + u.y*n.y + u.z*n.z + u.w*n.w;
    }
    for (int s = 8; s > 0; s >>= 1) {
        ps += __shfl_xor(ps, s, 16);
        ns += __shfl_xor(ns, s, 16);
    }
    float term = 0.0f;
    if (q == 0 && i < BATCH) {
        float d = (ps - ns) * (1.0f / 16.0f);
        float sig = 1.0f / (1.0f + expf(-d));
        term = logf(sig + 1e-8f);
    }
    float bt = block_reduce_sum(term);
    if (threadIdx.x == 0) unsafeAtomicAdd(loss_sum, bt);
}

// f32 gather-add + score (fallback path)
__global__ void gather_add_kernel(const float* __restrict__ x,
                                  const int* __restrict__ users, const int* __restrict__ pos,
                                  const int* __restrict__ neg,
                                  float* __restrict__ uacc, float* __restrict__ pacc,
                                  float* __restrict__ nacc) {
    int tid = blockIdx.x * blockDim.x + threadIdx.x;
    int i = tid >> 4;
    int q = tid & 15;
    if (i >= BATCH) return;
    size_t o = (size_t)i * DIM + q * 4;
    float4 a, b;
    a = *(float4*)(uacc + o);
    b = *(const float4*)(x + (size_t)users[i] * DIM + q * 4);
    a.x += b.x; a.y += b.y; a.z += b.z; a.w += b.w;
    *(float4*)(uacc + o) = a;
    a = *(float4*)(pacc + o);
    b = *(const float4*)(x + (size_t)(N_USERS + pos[i]) * DIM + q * 4);
    a.x += b.x; a.y += b.y; a.z += b.z; a.w += b.w;
    *(float4*)(pacc + o) = a;
    a = *(float4*)(nacc + o);
    b = *(const float4*)(x + (size_t)(N_USERS + neg[i]) * DIM + q * 4);
    a.x += b.x; a.y += b.y; a.z += b.z; a.w += b.w;
    *(float4*)(nacc + o) = a;
}

__global__ void score_kernel(const float* __restrict__ uacc, const float* __restrict__ pacc,
                             const float* __restrict__ nacc, float* __restrict__ loss_sum) {
    int tid = blockIdx.x * blockDim.x + threadIdx.x;
    int i = tid >> 4;
    int q = tid & 15;
    float ps = 0.0f, ns = 0.0f;
    if (i < BATCH) {
        size_t o = (size_t)i * DIM + q * 4;
        float4 u = *(const float4*)(uacc + o);
        float4 p = *(const float4*)(pacc + o);
        float4 n = *(const float4*)(nacc + o);
        ps = u.x*p.x + u.y*p.y + u.z*p.z + u.w*p.w;
        ns = u.x*n.x + u.y*n.y + u.z*n.z + u.w*n.w;
    }
    for (int s = 8; s > 0; s >>= 1) {
        ps += __shfl_xor(ps, s, 16);
        ns += __shfl_xor(ns, s, 16);
    }
    float term = 0.0f;
    if (q == 0 && i < BATCH) {
        float d = (ps - ns) * (1.0f / 16.0f);
        float sig = 1.0f / (1.0f + expf(-d));
        term = logf(sig + 1e-8f);
    }
    float bt = block_reduce_sum(term);
    if (threadIdx.x == 0) unsafeAtomicAdd(loss_sum, bt);
}

__global__ void finalize_kernel(const float* __restrict__ sums, float* __restrict__ out) {
    if (threadIdx.x == 0 && blockIdx.x == 0) {
        out[0] = -sums[0] / (float)BATCH;
        out[1] =  sums[1] / (float)BATCH;
    }
}

static inline size_t align256(size_t x) { return (x + 255) & ~(size_t)255; }

extern "C" void kernel_launch(void* const* d_in, const int* in_sizes, int n_in,
                              void* d_out, int out_size, void* d_ws, size_t ws_size,
                              hipStream_t stream) {
    const float* uw   = (const float*)d_in[0];
    const float* iw   = (const float*)d_in[1];
    const float* vals = (const float*)d_in[2];
    const int*   rows = (const int*)d_in[3];
    const int*   cols = (const int*)d_in[4];
    const int*   users = (const int*)d_in[5];
    const int*   pos   = (const int*)d_in[6];
    const int*   neg   = (const int*)d_in[7];
    const int nnz = in_sizes[2];

    char* ws = (char*)d_ws;
    const size_t nodeBytes = (size_t)N_NODES * DIM * sizeof(float);   // 38.4 MB
    const size_t qBytes    = (size_t)N_NODES * DIM;                   // 9.6 MB (fp8)
    const size_t accBytes  = (size_t)BATCH * DIM * sizeof(float);

    size_t off = 0;
    char*  nodeReg = ws + off;            off += align256(2 * nodeBytes);   // 76.8 MB region
    float* uacc = (float*)(ws + off);     off += align256(accBytes);
    float* pacc = (float*)(ws + off);     off += align256(accBytes);
    float* nacc = (float*)(ws + off);     off += align256(accBytes);
    float* sums = (float*)(ws + off);     off += 256;   // [0]=loss, [1]=reg
    Pair*  perm = (Pair*)(ws + off);      off += align256((size_t)nnz * sizeof(Pair));
    int*   rowptr = (int*)(ws + off);     off += align256((size_t)(N_NODES + 1) * sizeof(int));
    int*   bbase  = (int*)(ws + off);     off += align256((size_t)(NB + 1) * sizeof(int));
    int*   bcursor= (int*)(ws + off);     off += align256((size_t)NB * sizeof(int));
    int*   flags  = (int*)(ws + off);     off += align256((size_t)N_NODES * sizeof(int));
    const bool fits_alias = (2 * align256(qBytes) + (size_t)NB * STRIDE * sizeof(Pair)) <= 2 * nodeBytes;
    const bool use_csr = (off <= ws_size) && fits_alias && (N_NODES < (1 << 18));

    unsigned char* xb0 = (unsigned char*)nodeReg;
    unsigned char* xb1 = (unsigned char*)(nodeReg + align256(qBytes));
    unsigned char* xb2 = (unsigned char*)(nodeReg + 2 * align256(qBytes));
    Pair*          bcv = (Pair*)(nodeReg + 2 * align256(qBytes));
    float* xA = (float*)nodeReg;
    float* xB = (float*)(nodeReg + nodeBytes);

    float* out = (float*)d_out;

    const int bthreads = BATCH * 16;
    const int bblocks  = bthreads / 256;
    const int tblocks  = (nnz + TILE_E - 1) / TILE_E;
    const int cblocks  = (int)(((size_t)N_NODES * DIM / 8 + 255) / 256);

    if (use_csr) {
        convert_kernel<<<cblocks, 256, 0, stream>>>(uw, iw, xb0, flags, bcursor);
        flag_kernel<<<(3 * BATCH + 255) / 256, 256, 0, stream>>>(users, pos, neg, flags, sums);
        init_kernel<<<bblocks, 256, 0, stream>>>(uw, iw, users, pos, neg, uacc, pacc, nacc, sums + 1);
        binned_scatter_kernel<<<tblocks, 512, 0, stream>>>(rows, cols, vals, bcursor, bcv, nnz);
        post_scan_kernel<<<1, 1024, 0, stream>>>(bcursor, bbase, rowptr, nnz);
        bucket_sort_kernel<<<NB, 256, 0, stream>>>(bcv, bcursor, bbase, rowptr, perm);

        const int sblocks = (N_NODES + 15) / 16;   // 16 rows per 256-thread block
        // Layer 1: xb0 -> xb1
        spmm_csr_f8_kernel<false><<<sblocks, 256, 0, stream>>>(xb0, perm, rowptr, flags, xb1);
        gather_add_f8_kernel<<<bblocks, 256, 0, stream>>>(xb1, users, pos, neg, uacc, pacc, nacc);
        // Layer 2: xb1 -> xb2 (bcv dead after sort)
        spmm_csr_f8_kernel<false><<<sblocks, 256, 0, stream>>>(xb1, perm, rowptr, flags, xb2);
        gather_add_f8_kernel<<<bblocks, 256, 0, stream>>>(xb2, users, pos, neg, uacc, pacc, nacc);
        // Layer 3: xb2 -> xb0, only flagged rows; fused gather+score epilogue
        spmm_csr_f8_kernel<true><<<sblocks, 256, 0, stream>>>(xb2, perm, rowptr, flags, xb0);
        gather_score_kernel<<<bblocks, 256, 0, stream>>>(xb0, users, pos, neg, uacc, pacc, nacc, sums);
    } else {
        const long long sthreads = (long long)nnz * 16;
        const int sblocks = (int)((sthreads + 255) / 256);
        (void)hipMemsetAsync(sums, 0, 2 * sizeof(float), stream);
        init_kernel<<<bblocks, 256, 0, stream>>>(uw, iw, users, pos, neg, uacc, pacc, nacc, sums + 1);
        (void)hipMemsetAsync(xA, 0, nodeBytes, stream);
        spmm_atomic_kernel<<<sblocks, 256, 0, stream>>>(uw, iw, vals, rows, cols, xA, nnz);
        gather_add_kernel<<<bblocks, 256, 0, stream>>>(xA, users, pos, neg, uacc, pacc, nacc);
        (void)hipMemsetAsync(xB, 0, nodeBytes, stream);
        spmm_atomic_kernel<<<sblocks, 256, 0, stream>>>(xA, xA + (size_t)N_USERS * DIM, vals, rows, cols, xB, nnz);
        gather_add_kernel<<<bblocks, 256, 0, stream>>>(xB, users, pos, neg, uacc, pacc, nacc);
        (void)hipMemsetAsync(xA, 0, nodeBytes, stream);
        spmm_atomic_kernel<<<sblocks, 256, 0, stream>>>(xB, xB + (size_t)N_USERS * DIM, vals, rows, cols, xA, nnz);
        gather_add_kernel<<<bblocks, 256, 0, stream>>>(xA, users, pos, neg, uacc, pacc, nacc);
        score_kernel<<<bblocks, 256, 0, stream>>>(uacc, pacc, nacc, sums);
    }

    finalize_kernel<<<1, 1, 0, stream>>>(sums, out);
}

// Round 13
// 250.531 us; speedup vs baseline: 1.0387x; 1.0387x over previous
//
#include <hip/hip_runtime.h>

#define N_USERS 100000
#define N_ITEMS 50000
#define N_NODES (N_USERS + N_ITEMS)
#define DIM 64
#define BATCH 16384
#define RPB 512                          // rows per bucket
#define BSHIFT 9                         // log2(RPB)
#define NB ((N_NODES + RPB - 1) / RPB)   // 293 buckets
#define HP 296                           // padded hist stride
#define EPT 8                            // edges per thread in scatter
#define TILE_E (512 * EPT)               // 4096 edges per scatter block
#define STRIDE 12288                     // bcv region stride (45-sigma headroom)
#define XSCALE 64.0f                     // fp8 storage scale
#define INV_XSCALE 0.015625f             // 1/64

struct __align__(8) Pair { int c; float v; };
typedef float floatx2 __attribute__((ext_vector_type(2)));

// ---- fp8 helpers (e4m3, gfx940+ builtins) ---------------------------------
__device__ __forceinline__ unsigned pk8(float a, float b, float c, float d) {
    int w = __builtin_amdgcn_cvt_pk_fp8_f32(a, b, 0, false);
    w = __builtin_amdgcn_cvt_pk_fp8_f32(c, d, w, true);
    return (unsigned)w;
}

// acc(a0..a3) += v * fp8x4(x)   — 2 cvt + 4 fma
#define EDGE_F8D(V, X) { \
    floatx2 lo_ = __builtin_amdgcn_cvt_pk_f32_fp8((X), false); \
    floatx2 hi_ = __builtin_amdgcn_cvt_pk_f32_fp8((X), true); \
    a0 = fmaf((V), lo_.x, a0); a1 = fmaf((V), lo_.y, a1); \
    a2 = fmaf((V), hi_.x, a2); a3 = fmaf((V), hi_.y, a3); }

// non-temporal Pair load (perm stream is read-once per pass)
__device__ __forceinline__ Pair ldnt(const Pair* p) {
    unsigned long long w = __builtin_nontemporal_load((const unsigned long long*)p);
    Pair r;
    r.c = (int)(unsigned)(w & 0xffffffffu);
    r.v = __uint_as_float((unsigned)(w >> 32));
    return r;
}

// ---------------------------------------------------------------------------
__device__ __forceinline__ float block_reduce_sum(float v) {
    for (int s = 32; s > 0; s >>= 1) v += __shfl_xor(v, s, 64);
    __shared__ float sm[8];
    int lane = threadIdx.x & 63;
    int wid  = threadIdx.x >> 6;
    if (lane == 0) sm[wid] = v;
    __syncthreads();
    float t = 0.0f;
    if (threadIdx.x == 0) {
        int nw = (blockDim.x + 63) >> 6;
        for (int w = 0; w < nw; ++w) t += sm[w];
    }
    return t;
}

// ---------------------------------------------------------------------------
// Convert concat [uw;iw] f32 -> fp8 (x64 scale). Also clears flags, bcursor,
// and the loss/reg sums (all consumed by later dispatches in stream order).
// ---------------------------------------------------------------------------
__global__ void convert_kernel(const float* __restrict__ uw, const float* __restrict__ iw,
                               unsigned char* __restrict__ x8,
                               int* __restrict__ flags, int* __restrict__ bcursor,
                               float* __restrict__ sums) {
    size_t tid = (size_t)blockIdx.x * 256 + threadIdx.x;
    if (tid < 2) sums[tid] = 0.0f;
    if (tid < N_NODES) flags[tid] = 0;
    else if (tid < N_NODES + NB) bcursor[tid - N_NODES] = 0;
    size_t base = tid * 8;
    if (base >= (size_t)N_NODES * DIM) return;
    const float* src = (base < (size_t)N_USERS * DIM) ? uw + base
                                                      : iw + (base - (size_t)N_USERS * DIM);
    float4 a = ((const float4*)src)[0];
    float4 b = ((const float4*)src)[1];
    uint2 o;
    o.x = pk8(XSCALE * a.x, XSCALE * a.y, XSCALE * a.z, XSCALE * a.w);
    o.y = pk8(XSCALE * b.x, XSCALE * b.y, XSCALE * b.z, XSCALE * b.w);
    *(uint2*)(x8 + base) = o;
}

// ---------------------------------------------------------------------------
// Init: acc_0 = gathered layer-0 embeddings + reg_sum from ORIGINAL weights.
// Also sets the layer-3 row flags (flags were cleared by convert_kernel).
// ---------------------------------------------------------------------------
__global__ void init_kernel(const float* __restrict__ uw, const float* __restrict__ iw,
                            const int* __restrict__ users, const int* __restrict__ pos,
                            const int* __restrict__ neg,
                            float* __restrict__ uacc, float* __restrict__ pacc,
                            float* __restrict__ nacc, float* __restrict__ reg_sum,
                            int* __restrict__ flags) {
    int tid = blockIdx.x * blockDim.x + threadIdx.x;
    if (tid < BATCH)          flags[users[tid]] = 1;
    else if (tid < 2 * BATCH) flags[N_USERS + pos[tid - BATCH]] = 1;
    else if (tid < 3 * BATCH) flags[N_USERS + neg[tid - 2 * BATCH]] = 1;
    int i = tid >> 4;
    int q = tid & 15;
    if (i >= BATCH) return;
    size_t o = (size_t)i * DIM + q * 4;
    float4 u = *(const float4*)(uw + (size_t)users[i] * DIM + q * 4);
    float4 p = *(const float4*)(iw + (size_t)pos[i]   * DIM + q * 4);
    float4 n = *(const float4*)(iw + (size_t)neg[i]   * DIM + q * 4);
    *(float4*)(uacc + o) = u;
    *(float4*)(pacc + o) = p;
    *(float4*)(nacc + o) = n;
    float ss = u.x*u.x + u.y*u.y + u.z*u.z + u.w*u.w
             + p.x*p.x + p.y*p.y + p.z*p.z + p.w*p.w
             + n.x*n.x + n.y*n.y + n.z*n.z + n.w*n.w;
    float bt = block_reduce_sum(ss);
    if (threadIdx.x == 0) unsafeAtomicAdd(reg_sum, bt);
}

// ---------------------------------------------------------------------------
// Binned scatter into fixed-stride per-bucket regions. All global loads in
// phase 1; per-wave LDS hist; one packed 8B store per edge.
// packed c-field = col | (row_local << 18)   (col < 2^18, row_local < 512)
// ---------------------------------------------------------------------------
__global__ void binned_scatter_kernel(const int* __restrict__ rows, const int* __restrict__ cols,
                                      const float* __restrict__ vals, int* __restrict__ bcursor,
                                      Pair* __restrict__ bcv, int nnz) {
    __shared__ int h[8][HP];
    int t = threadIdx.x, w = t >> 6;
    for (int i = t; i < 8 * HP; i += 512) ((int*)h)[i] = 0;
    __syncthreads();
    long long tile = (long long)blockIdx.x * TILE_E;
    int er[EPT], cr[EPT];
    float vr[EPT];
    #pragma unroll
    for (int j = 0; j < EPT; ++j) {
        long long e = tile + t + j * 512;
        if (e < nnz) {
            int r = rows[e];
            er[j] = r;
            cr[j] = cols[e];
            vr[j] = vals[e];
            atomicAdd(&h[w][r >> BSHIFT], 1);
        } else er[j] = -1;
    }
    __syncthreads();
    for (int b = t; b < NB; b += 512) {
        int cw[8], tot = 0;
        #pragma unroll
        for (int w2 = 0; w2 < 8; ++w2) { cw[w2] = h[w2][b]; tot += cw[w2]; }
        int base = tot ? (b * STRIDE + atomicAdd(&bcursor[b], tot)) : 0;
        #pragma unroll
        for (int w2 = 0; w2 < 8; ++w2) { h[w2][b] = base; base += cw[w2]; }
    }
    __syncthreads();
    #pragma unroll
    for (int j = 0; j < EPT; ++j) {
        if (er[j] >= 0) {
            int r = er[j];
            int dst = atomicAdd(&h[w][r >> BSHIFT], 1);
            Pair p;
            p.c = cr[j] | ((r & (RPB - 1)) << 18);
            p.v = vr[j];
            bcv[dst] = p;
        }
    }
}

// ---------------------------------------------------------------------------
// Post-scan: bucket counts -> dense CSR bucket bases (NB=293 <= 512).
// ---------------------------------------------------------------------------
__global__ void post_scan_kernel(const int* __restrict__ counts, int* __restrict__ bbase,
                                 int* __restrict__ rowptr, int nnz) {
    __shared__ int sm[512];
    int t = threadIdx.x;
    int v = (t < NB) ? counts[t] : 0;
    sm[t] = v;
    __syncthreads();
    for (int off = 1; off < 512; off <<= 1) {
        int tmp = (t >= off) ? sm[t - off] : 0;
        __syncthreads();
        sm[t] += tmp;
        __syncthreads();
    }
    if (t < NB) bbase[t] = sm[t] - v;
    if (t == 511) bbase[NB] = sm[511];
    if (t == 0) rowptr[N_NODES] = nnz;
}

// ---------------------------------------------------------------------------
// Per-bucket counting sort in LDS -> final dense CSR perm + rowptr.
// 512 threads, 293 blocks; 8-way wave-replicated hist.
// ---------------------------------------------------------------------------
__global__ void bucket_sort_kernel(const Pair* __restrict__ bcv,
                                   const int* __restrict__ counts,
                                   const int* __restrict__ bbase,
                                   int* __restrict__ rowptr, Pair* __restrict__ perm) {
    __shared__ int rh8[8][RPB + 8];
    __shared__ int rh[RPB];
    __shared__ int sc[RPB];
    int blk = blockIdx.x;
    int t = threadIdx.x;        // 512 threads
    int w = t >> 6;
    size_t src = (size_t)blk * STRIDE;
    int base = bbase[blk];
    int cnt  = counts[blk];
    for (int i = t; i < 8 * (RPB + 8); i += 512) ((int*)rh8)[i] = 0;
    __syncthreads();
    for (int i = t; i < cnt; i += 512)
        atomicAdd(&rh8[w][(unsigned)bcv[src + i].c >> 18], 1);
    __syncthreads();
    int v = 0;
    #pragma unroll
    for (int w2 = 0; w2 < 8; ++w2) v += rh8[w2][t];
    sc[t] = v;
    __syncthreads();
    for (int off = 1; off < 512; off <<= 1) {
        int tmp = (t >= off) ? sc[t - off] : 0;
        __syncthreads();
        sc[t] += tmp;
        __syncthreads();
    }
    int excl = sc[t] - v;
    int g = blk * RPB + t;
    if (g < N_NODES) rowptr[g] = base + excl;
    rh[t] = excl;
    __syncthreads();
    for (int i = t; i < cnt; i += 512) {
        Pair p = bcv[src + i];
        int r = (unsigned)p.c >> 18;
        int rk = atomicAdd(&rh[r], 1);
        p.c &= 0x3FFFF;
        perm[base + rk] = p;
    }
}

// ---------------------------------------------------------------------------
// CSR SpMM, fp8 in / fp8 out (f32 accumulate). 16 lanes per ROW (one dword
// = 4 dims per lane); 8-deep edge unroll; zero shuffles; nt perm loads.
// ---------------------------------------------------------------------------
template<bool FLAGGED>
__global__ void spmm_csr_f8_kernel(const unsigned char* __restrict__ x8,
                                   const Pair* __restrict__ pe,
                                   const int* __restrict__ rowptr,
                                   const int* __restrict__ flags,
                                   unsigned char* __restrict__ out8) {
    int row = blockIdx.x * 16 + (threadIdx.x >> 4);
    if (row >= N_NODES) return;
    if (FLAGGED && !flags[row]) return;
    int q = threadIdx.x & 15;        // dword slot (4 dims)
    int start = rowptr[row];
    int end   = rowptr[row + 1];
    float a0 = 0.f, a1 = 0.f, a2 = 0.f, a3 = 0.f;
    int e = start;
    for (; e + 7 < end; e += 8) {
        Pair p0 = ldnt(pe + e),     p1 = ldnt(pe + e + 1);
        Pair p2 = ldnt(pe + e + 2), p3 = ldnt(pe + e + 3);
        Pair p4 = ldnt(pe + e + 4), p5 = ldnt(pe + e + 5);
        Pair p6 = ldnt(pe + e + 6), p7 = ldnt(pe + e + 7);
        unsigned x0 = *(const unsigned*)(x8 + ((size_t)p0.c << 6) + q * 4);
        unsigned x1 = *(const unsigned*)(x8 + ((size_t)p1.c << 6) + q * 4);
        unsigned x2 = *(const unsigned*)(x8 + ((size_t)p2.c << 6) + q * 4);
        unsigned x3 = *(const unsigned*)(x8 + ((size_t)p3.c << 6) + q * 4);
        unsigned x4 = *(const unsigned*)(x8 + ((size_t)p4.c << 6) + q * 4);
        unsigned x5 = *(const unsigned*)(x8 + ((size_t)p5.c << 6) + q * 4);
        unsigned x6 = *(const unsigned*)(x8 + ((size_t)p6.c << 6) + q * 4);
        unsigned x7 = *(const unsigned*)(x8 + ((size_t)p7.c << 6) + q * 4);
        EDGE_F8D(p0.v, x0); EDGE_F8D(p1.v, x1);
        EDGE_F8D(p2.v, x2); EDGE_F8D(p3.v, x3);
        EDGE_F8D(p4.v, x4); EDGE_F8D(p5.v, x5);
        EDGE_F8D(p6.v, x6); EDGE_F8D(p7.v, x7);
    }
    for (; e + 1 < end; e += 2) {
        Pair p0 = ldnt(pe + e), p1 = ldnt(pe + e + 1);
        unsigned x0 = *(const unsigned*)(x8 + ((size_t)p0.c << 6) + q * 4);
        unsigned x1 = *(const unsigned*)(x8 + ((size_t)p1.c << 6) + q * 4);
        EDGE_F8D(p0.v, x0); EDGE_F8D(p1.v, x1);
    }
    if (e < end) {
        Pair p = ldnt(pe + e);
        unsigned x = *(const unsigned*)(x8 + ((size_t)p.c << 6) + q * 4);
        EDGE_F8D(p.v, x);
    }
    *(unsigned*)(out8 + ((size_t)row << 6) + q * 4) = pk8(a0, a1, a2, a3);
}

// ---------------------------------------------------------------------------
// Legacy COO atomic SpMM (fallback).
// ---------------------------------------------------------------------------
__global__ void spmm_atomic_kernel(const float* __restrict__ xu, const float* __restrict__ xi,
                                   const float* __restrict__ vals, const int* __restrict__ rows,
                                   const int* __restrict__ cols,
                                   float* __restrict__ out, int nnz) {
    long long tid = (long long)blockIdx.x * blockDim.x + threadIdx.x;
    int e = (int)(tid >> 4);
    if (e >= nnz) return;
    int q = (int)(tid & 15);
    int r = rows[e];
    int c = cols[e];
    float v = vals[e];
    const float* src = (c < N_USERS) ? (xu + (size_t)c * DIM)
                                     : (xi + (size_t)(c - N_USERS) * DIM);
    float4 x = *(const float4*)(src + q * 4);
    float* dst = out + (size_t)r * DIM + q * 4;
    unsafeAtomicAdd(dst + 0, v * x.x);
    unsafeAtomicAdd(dst + 1, v * x.y);
    unsafeAtomicAdd(dst + 2, v * x.z);
    unsafeAtomicAdd(dst + 3, v * x.w);
}

// ---------------------------------------------------------------------------
// Gather-accumulate a layer's fp8 output at the batch rows only (unscale).
// ---------------------------------------------------------------------------
__global__ void gather_add_f8_kernel(const unsigned char* __restrict__ x8,
                                     const int* __restrict__ users, const int* __restrict__ pos,
                                     const int* __restrict__ neg,
                                     float* __restrict__ uacc, float* __restrict__ pacc,
                                     float* __restrict__ nacc) {
    int tid = blockIdx.x * blockDim.x + threadIdx.x;
    int i = tid >> 4;
    int q = tid & 15;
    if (i >= BATCH) return;
    size_t o = (size_t)i * DIM + q * 4;
    float4 a;
    unsigned u;
    floatx2 lo, hi;

    a = *(float4*)(uacc + o);
    u = *(const unsigned*)(x8 + ((size_t)users[i] << 6) + q * 4);
    lo = __builtin_amdgcn_cvt_pk_f32_fp8(u, false);
    hi = __builtin_amdgcn_cvt_pk_f32_fp8(u, true);
    a.x = fmaf(lo.x, INV_XSCALE, a.x); a.y = fmaf(lo.y, INV_XSCALE, a.y);
    a.z = fmaf(hi.x, INV_XSCALE, a.z); a.w = fmaf(hi.y, INV_XSCALE, a.w);
    *(float4*)(uacc + o) = a;

    a = *(float4*)(pacc + o);
    u = *(const unsigned*)(x8 + ((size_t)(N_USERS + pos[i]) << 6) + q * 4);
    lo = __builtin_amdgcn_cvt_pk_f32_fp8(u, false);
    hi = __builtin_amdgcn_cvt_pk_f32_fp8(u, true);
    a.x = fmaf(lo.x, INV_XSCALE, a.x); a.y = fmaf(lo.y, INV_XSCALE, a.y);
    a.z = fmaf(hi.x, INV_XSCALE, a.z); a.w = fmaf(hi.y, INV_XSCALE, a.w);
    *(float4*)(pacc + o) = a;

    a = *(float4*)(nacc + o);
    u = *(const unsigned*)(x8 + ((size_t)(N_USERS + neg[i]) << 6) + q * 4);
    lo = __builtin_amdgcn_cvt_pk_f32_fp8(u, false);
    hi = __builtin_amdgcn_cvt_pk_f32_fp8(u, true);
    a.x = fmaf(lo.x, INV_XSCALE, a.x); a.y = fmaf(lo.y, INV_XSCALE, a.y);
    a.z = fmaf(hi.x, INV_XSCALE, a.z); a.w = fmaf(hi.y, INV_XSCALE, a.w);
    *(float4*)(nacc + o) = a;
}

// ---------------------------------------------------------------------------
// Fused layer-3 gather + BPR score. final = acc/4, so dot scales by 1/16.
// ---------------------------------------------------------------------------
__global__ void gather_score_kernel(const unsigned char* __restrict__ x8,
                                    const int* __restrict__ users, const int* __restrict__ pos,
                                    const int* __restrict__ neg,
                                    const float* __restrict__ uacc, const float* __restrict__ pacc,
                                    const float* __restrict__ nacc, float* __restrict__ loss_sum) {
    int tid = blockIdx.x * blockDim.x + threadIdx.x;
    int i = tid >> 4;
    int q = tid & 15;
    float ps = 0.0f, ns = 0.0f;
    if (i < BATCH) {
        size_t o = (size_t)i * DIM + q * 4;
        float4 u = *(const float4*)(uacc + o);
        float4 p = *(const float4*)(pacc + o);
        float4 n = *(const float4*)(nacc + o);
        unsigned t;
        floatx2 lo, hi;
        t = *(const unsigned*)(x8 + ((size_t)users[i] << 6) + q * 4);
        lo = __builtin_amdgcn_cvt_pk_f32_fp8(t, false);
        hi = __builtin_amdgcn_cvt_pk_f32_fp8(t, true);
        u.x = fmaf(lo.x, INV_XSCALE, u.x); u.y = fmaf(lo.y, INV_XSCALE, u.y);
        u.z = fmaf(hi.x, INV_XSCALE, u.z); u.w = fmaf(hi.y, INV_XSCALE, u.w);
        t = *(const unsigned*)(x8 + ((size_t)(N_USERS + pos[i]) << 6) + q * 4);
        lo = __builtin_amdgcn_cvt_pk_f32_fp8(t, false);
        hi = __builtin_amdgcn_cvt_pk_f32_fp8(t, true);
        p.x = fmaf(lo.x, INV_XSCALE, p.x); p.y = fmaf(lo.y, INV_XSCALE, p.y);
        p.z = fmaf(hi.x, INV_XSCALE, p.z); p.w = fmaf(hi.y, INV_XSCALE, p.w);
        t = *(const unsigned*)(x8 + ((size_t)(N_USERS + neg[i]) << 6) + q * 4);
        lo = __builtin_amdgcn_cvt_pk_f32_fp8(t, false);
        hi = __builtin_amdgcn_cvt_pk_f32_fp8(t, true);
        n.x = fmaf(lo.x, INV_XSCALE, n.x); n.y = fmaf(lo.y, INV_XSCALE, n.y);
        n.z = fmaf(hi.x, INV_XSCALE, n.z); n.w = fmaf(hi.y, INV_XSCALE, n.w);
        ps = u.x*p.x + u.y*p.y + u.z*p.z + u.w*p.w;
        ns = u.x*n.x + u.y*n.y + u.z*n.z + u.w*n.w;
    }
    for (int s = 8; s > 0; s >>= 1) {
        ps += __shfl_xor(ps, s, 16);
        ns += __shfl_xor(ns, s, 16);
    }
    float term = 0.0f;
    if (q == 0 && i < BATCH) {
        float d = (ps - ns) * (1.0f / 16.0f);
        float sig = 1.0f / (1.0f + expf(-d));
        term = logf(sig + 1e-8f);
    }
    float bt = block_reduce_sum(term);
    if (threadIdx.x == 0) unsafeAtomicAdd(loss_sum, bt);
}

// f32 gather-add + score (fallback path)
__global__ void gather_add_kernel(const float* __restrict__ x,
                                  const int* __restrict__ users, const int* __restrict__ pos,
                                  const int* __restrict__ neg,
                                  float* __restrict__ uacc, float* __restrict__ pacc,
                                  float* __restrict__ nacc) {
    int tid = blockIdx.x * blockDim.x + threadIdx.x;
    int i = tid >> 4;
    int q = tid & 15;
    if (i >= BATCH) return;
    size_t o = (size_t)i * DIM + q * 4;
    float4 a, b;
    a = *(float4*)(uacc + o);
    b = *(const float4*)(x + (size_t)users[i] * DIM + q * 4);
    a.x += b.x; a.y += b.y; a.z += b.z; a.w += b.w;
    *(float4*)(uacc + o) = a;
    a = *(float4*)(pacc + o);
    b = *(const float4*)(x + (size_t)(N_USERS + pos[i]) * DIM + q * 4);
    a.x += b.x; a.y += b.y; a.z += b.z; a.w += b.w;
    *(float4*)(pacc + o) = a;
    a = *(float4*)(nacc + o);
    b = *(const float4*)(x + (size_t)(N_USERS + neg[i]) * DIM + q * 4);
    a.x += b.x; a.y += b.y; a.z += b.z; a.w += b.w;
    *(float4*)(nacc + o) = a;
}

__global__ void score_kernel(const float* __restrict__ uacc, const float* __restrict__ pacc,
                             const float* __restrict__ nacc, float* __restrict__ loss_sum) {
    int tid = blockIdx.x * blockDim.x + threadIdx.x;
    int i = tid >> 4;
    int q = tid & 15;
    float ps = 0.0f, ns = 0.0f;
    if (i < BATCH) {
        size_t o = (size_t)i * DIM + q * 4;
        float4 u = *(const float4*)(uacc + o);
        float4 p = *(const float4*)(pacc + o);
        float4 n = *(const float4*)(nacc + o);
        ps = u.x*p.x + u.y*p.y + u.z*p.z + u.w*p.w;
        ns = u.x*n.x + u.y*n.y + u.z*n.z + u.w*n.w;
    }
    for (int s = 8; s > 0; s >>= 1) {
        ps += __shfl_xor(ps, s, 16);
        ns += __shfl_xor(ns, s, 16);
    }
    float term = 0.0f;
    if (q == 0 && i < BATCH) {
        float d = (ps - ns) * (1.0f / 16.0f);
        float sig = 1.0f / (1.0f + expf(-d));
        term = logf(sig + 1e-8f);
    }
    float bt = block_reduce_sum(term);
    if (threadIdx.x == 0) unsafeAtomicAdd(loss_sum, bt);
}

__global__ void finalize_kernel(const float* __restrict__ sums, float* __restrict__ out) {
    if (threadIdx.x == 0 && blockIdx.x == 0) {
        out[0] = -sums[0] / (float)BATCH;
        out[1] =  sums[1] / (float)BATCH;
    }
}

static inline size_t align256(size_t x) { return (x + 255) & ~(size_t)255; }

extern "C" void kernel_launch(void* const* d_in, const int* in_sizes, int n_in,
                              void* d_out, int out_size, void* d_ws, size_t ws_size,
                              hipStream_t stream) {
    const float* uw   = (const float*)d_in[0];
    const float* iw   = (const float*)d_in[1];
    const float* vals = (const float*)d_in[2];
    const int*   rows = (const int*)d_in[3];
    const int*   cols = (const int*)d_in[4];
    const int*   users = (const int*)d_in[5];
    const int*   pos   = (const int*)d_in[6];
    const int*   neg   = (const int*)d_in[7];
    const int nnz = in_sizes[2];

    char* ws = (char*)d_ws;
    const size_t nodeBytes = (size_t)N_NODES * DIM * sizeof(float);   // 38.4 MB
    const size_t qBytes    = (size_t)N_NODES * DIM;                   // 9.6 MB (fp8)
    const size_t accBytes  = (size_t)BATCH * DIM * sizeof(float);

    size_t off = 0;
    char*  nodeReg = ws + off;            off += align256(2 * nodeBytes);   // 76.8 MB region
    float* uacc = (float*)(ws + off);     off += align256(accBytes);
    float* pacc = (float*)(ws + off);     off += align256(accBytes);
    float* nacc = (float*)(ws + off);     off += align256(accBytes);
    float* sums = (float*)(ws + off);     off += 256;   // [0]=loss, [1]=reg
    Pair*  perm = (Pair*)(ws + off);      off += align256((size_t)nnz * sizeof(Pair));
    int*   rowptr = (int*)(ws + off);     off += align256((size_t)(N_NODES + 1) * sizeof(int));
    int*   bbase  = (int*)(ws + off);     off += align256((size_t)(NB + 1) * sizeof(int));
    int*   bcursor= (int*)(ws + off);     off += align256((size_t)NB * sizeof(int));
    int*   flags  = (int*)(ws + off);     off += align256((size_t)N_NODES * sizeof(int));
    const bool fits_alias = (2 * align256(qBytes) + (size_t)NB * STRIDE * sizeof(Pair)) <= 2 * nodeBytes;
    const bool use_csr = (off <= ws_size) && fits_alias && (N_NODES < (1 << 18));

    unsigned char* xb0 = (unsigned char*)nodeReg;
    unsigned char* xb1 = (unsigned char*)(nodeReg + align256(qBytes));
    unsigned char* xb2 = (unsigned char*)(nodeReg + 2 * align256(qBytes));
    Pair*          bcv = (Pair*)(nodeReg + 2 * align256(qBytes));
    float* xA = (float*)nodeReg;
    float* xB = (float*)(nodeReg + nodeBytes);

    float* out = (float*)d_out;

    const int bthreads = BATCH * 16;
    const int bblocks  = bthreads / 256;
    const int tblocks  = (nnz + TILE_E - 1) / TILE_E;
    const int cblocks  = (int)(((size_t)N_NODES * DIM / 8 + 255) / 256);

    if (use_csr) {
        convert_kernel<<<cblocks, 256, 0, stream>>>(uw, iw, xb0, flags, bcursor, sums);
        init_kernel<<<bblocks, 256, 0, stream>>>(uw, iw, users, pos, neg, uacc, pacc, nacc, sums + 1, flags);
        binned_scatter_kernel<<<tblocks, 512, 0, stream>>>(rows, cols, vals, bcursor, bcv, nnz);
        post_scan_kernel<<<1, 512, 0, stream>>>(bcursor, bbase, rowptr, nnz);
        bucket_sort_kernel<<<NB, 512, 0, stream>>>(bcv, bcursor, bbase, rowptr, perm);

        const int sblocks = (N_NODES + 15) / 16;   // 16 rows per 256-thread block
        // Layer 1: xb0 -> xb1
        spmm_csr_f8_kernel<false><<<sblocks, 256, 0, stream>>>(xb0, perm, rowptr, flags, xb1);
        gather_add_f8_kernel<<<bblocks, 256, 0, stream>>>(xb1, users, pos, neg, uacc, pacc, nacc);
        // Layer 2: xb1 -> xb2 (bcv dead after sort)
        spmm_csr_f8_kernel<false><<<sblocks, 256, 0, stream>>>(xb1, perm, rowptr, flags, xb2);
        gather_add_f8_kernel<<<bblocks, 256, 0, stream>>>(xb2, users, pos, neg, uacc, pacc, nacc);
        // Layer 3: xb2 -> xb0, only flagged rows; fused gather+score epilogue
        spmm_csr_f8_kernel<true><<<sblocks, 256, 0, stream>>>(xb2, perm, rowptr, flags, xb0);
        gather_score_kernel<<<bblocks, 256, 0, stream>>>(xb0, users, pos, neg, uacc, pacc, nacc, sums);
    } else {
        const long long sthreads = (long long)nnz * 16;
        const int sblocks = (int)((sthreads + 255) / 256);
        (void)hipMemsetAsync(sums, 0, 2 * sizeof(float), stream);
        init_kernel<<<bblocks, 256, 0, stream>>>(uw, iw, users, pos, neg, uacc, pacc, nacc, sums + 1, flags);
        (void)hipMemsetAsync(xA, 0, nodeBytes, stream);
        spmm_atomic_kernel<<<sblocks, 256, 0, stream>>>(uw, iw, vals, rows, cols, xA, nnz);
        gather_add_kernel<<<bblocks, 256, 0, stream>>>(xA, users, pos, neg, uacc, pacc, nacc);
        (void)hipMemsetAsync(xB, 0, nodeBytes, stream);
        spmm_atomic_kernel<<<sblocks, 256, 0, stream>>>(xA, xA + (size_t)N_USERS * DIM, vals, rows, cols, xB, nnz);
        gather_add_kernel<<<bblocks, 256, 0, stream>>>(xB, users, pos, neg, uacc, pacc, nacc);
        (void)hipMemsetAsync(xA, 0, nodeBytes, stream);
        spmm_atomic_kernel<<<sblocks, 256, 0, stream>>>(xB, xB + (size_t)N_USERS * DIM, vals, rows, cols, xA, nnz);
        gather_add_kernel<<<bblocks, 256, 0, stream>>>(xA, users, pos, neg, uacc, pacc, nacc);
        score_kernel<<<bblocks, 256, 0, stream>>>(uacc, pacc, nacc, sums);
    }

    finalize_kernel<<<1, 1, 0, stream>>>(sums, out);
}